// Round 2
// baseline (487.211 us; speedup 1.0000x reference)
//
#include <hip/hip_runtime.h>
#include <math.h>

#define THREADS 256
#define ROWS 2   // rows per thread: each scalar weight load feeds ROWS FMAs
// fp32-vs-fp64 p error is <~4e-6 worst case (incl. v_exp_f32); 1e-4 margin
// is ~25x safety.
#define P_MARGIN 1e-4f
#define FIXCAP 32

typedef float v2f __attribute__((ext_vector_type(2)));

// Exact JAX threefry2x32 (20 rounds, key schedule every 4), key = (0, 42).
// Partitionable stream: bits[j] = o0 ^ o1 of threefry2x32(key, 0, j).
__device__ __forceinline__ void tf2x32(unsigned x0, unsigned x1,
                                       unsigned &o0, unsigned &o1) {
  const unsigned k0 = 0u;
  const unsigned k1 = 42u;
  const unsigned k2 = 0x1BD11BDAu ^ k0 ^ k1;
  x0 += k0; x1 += k1;
#define TF_R(r) { x0 += x1; x1 = (x1 << (r)) | (x1 >> (32 - (r))); x1 ^= x0; }
  TF_R(13) TF_R(15) TF_R(26) TF_R(6)
  x0 += k1; x1 += k2 + 1u;
  TF_R(17) TF_R(29) TF_R(16) TF_R(24)
  x0 += k2; x1 += k0 + 2u;
  TF_R(13) TF_R(15) TF_R(26) TF_R(6)
  x0 += k0; x1 += k1 + 3u;
  TF_R(17) TF_R(29) TF_R(16) TF_R(24)
  x0 += k1; x1 += k2 + 4u;
  TF_R(13) TF_R(15) TF_R(26) TF_R(6)
  x0 += k2; x1 += k0 + 5u;
#undef TF_R
  o0 = x0; o1 = x1;
}

// Single fused kernel, R1->R2 change: ROWS=2 row-tiling.
//  - Weights arrive via s_load (uniform addresses). The wave's ~102-SGPR cap
//    allows only ~1 k-iteration of s_load lookahead, so with 1 row/thread
//    each k-step had ~50cy of VALU cover vs ~100cy K$ latency -> ~50% stall
//    floor (VALUBusy measured 25%). Each weight now feeds ROWS=2 FMAs:
//    cover doubles, s_load stream unchanged.
//  - fp32 fast path numerics are bit-identical per row to the R1 kernel
//    except expf/logf -> __expf/__logf (HW exp/log, ~1e-6 rel; margin 1e-4).
//  - rows whose bernoulli comparison is within P_MARGIN of the threshold go
//    to a per-block LDS list; after a barrier the block cooperatively re-runs
//    them in fp64 (lane=neuron) and overwrites. Expected ~0.8 flagged
//    rows/block (512 rows/block); cap 32.
__global__ __launch_bounds__(THREADS, 2)
void wtf_kernel(const float* __restrict__ events,
                const float* __restrict__ W1, const float* __restrict__ b1,
                const float* __restrict__ g1, const float* __restrict__ be1,
                const float* __restrict__ W2, const float* __restrict__ b2,
                const float* __restrict__ g2, const float* __restrict__ be2,
                const float* __restrict__ W3, const float* __restrict__ b3,
                const float* __restrict__ g3, const float* __restrict__ be3,
                const float* __restrict__ W4, const float* __restrict__ b4,
                const float* __restrict__ W5, const float* __restrict__ b5,
                float* __restrict__ out_chosen,
                float* __restrict__ out_logp,
                int B) {
  __shared__ unsigned s_cnt;
  __shared__ unsigned s_rows[FIXCAP];
  __shared__ double sA[64];
  __shared__ double sB[64];
  __shared__ double sF[8];

  const int t = threadIdx.x;
  if (t == 0) s_cnt = 0;
  __syncthreads();

  const int row0 = blockIdx.x * (THREADS * ROWS) + t;  // row for r=0
  // r=1 handles row0 + THREADS (coalesced within the wave for both rows)
  const float rden = (float)(1.0 / sqrt(1.0 + 1e-5));

  bool act[ROWS];
#pragma unroll
  for (int r = 0; r < ROWS; ++r) act[r] = (row0 + r * THREADS) < B;

  if (act[0]) {  // B % (THREADS*ROWS) == 0 in this problem; act[] guards stores
    float x[ROWS][32];
#pragma unroll
    for (int r = 0; r < ROWS; ++r) {
      const float4* ev4 =
          reinterpret_cast<const float4*>(events) + (size_t)(row0 + r * THREADS) * 8;
#pragma unroll
      for (int q = 0; q < 8; ++q) {
        float4 v = ev4[q];
        x[r][4 * q + 0] = v.x; x[r][4 * q + 1] = v.y;
        x[r][4 * q + 2] = v.z; x[r][4 * q + 3] = v.w;
      }
    }

    // ---- layer 1: 32 -> 50, BN + ReLU (packed f32x2 accumulators) ----
    v2f A[ROWS][25];
#pragma unroll
    for (int j = 0; j < 25; ++j) {
      const v2f bb = {b1[2 * j], b1[2 * j + 1]};
#pragma unroll
      for (int r = 0; r < ROWS; ++r) A[r][j] = bb;
    }
#pragma unroll
    for (int k = 0; k < 32; ++k) {
#pragma unroll
      for (int j = 0; j < 25; ++j) {
        const v2f w = {W1[k * 50 + 2 * j], W1[k * 50 + 2 * j + 1]};
#pragma unroll
        for (int r = 0; r < ROWS; ++r) {
          const v2f xk2 = {x[r][k], x[r][k]};
          A[r][j] = __builtin_elementwise_fma(xk2, w, A[r][j]);
        }
      }
    }
    float a1[ROWS][50];
#pragma unroll
    for (int j = 0; j < 25; ++j) {
      const float s0 = g1[2 * j + 0] * rden, s1 = g1[2 * j + 1] * rden;
      const float o0 = be1[2 * j + 0],       o1 = be1[2 * j + 1];
#pragma unroll
      for (int r = 0; r < ROWS; ++r) {
        a1[r][2 * j + 0] = fmaxf(fmaf(A[r][j].x, s0, o0), 0.f);
        a1[r][2 * j + 1] = fmaxf(fmaf(A[r][j].y, s1, o1), 0.f);
      }
    }

    // ---- layer 2: 50 -> 30, BN + ReLU ----
    v2f C[ROWS][15];
#pragma unroll
    for (int j = 0; j < 15; ++j) {
      const v2f bb = {b2[2 * j], b2[2 * j + 1]};
#pragma unroll
      for (int r = 0; r < ROWS; ++r) C[r][j] = bb;
    }
#pragma unroll
    for (int k = 0; k < 50; ++k) {
#pragma unroll
      for (int j = 0; j < 15; ++j) {
        const v2f w = {W2[k * 30 + 2 * j], W2[k * 30 + 2 * j + 1]};
#pragma unroll
        for (int r = 0; r < ROWS; ++r) {
          const v2f hk2 = {a1[r][k], a1[r][k]};
          C[r][j] = __builtin_elementwise_fma(hk2, w, C[r][j]);
        }
      }
    }
    float a2[ROWS][30];
#pragma unroll
    for (int j = 0; j < 15; ++j) {
      const float s0 = g2[2 * j + 0] * rden, s1 = g2[2 * j + 1] * rden;
      const float o0 = be2[2 * j + 0],       o1 = be2[2 * j + 1];
#pragma unroll
      for (int r = 0; r < ROWS; ++r) {
        a2[r][2 * j + 0] = fmaxf(fmaf(C[r][j].x, s0, o0), 0.f);
        a2[r][2 * j + 1] = fmaxf(fmaf(C[r][j].y, s1, o1), 0.f);
      }
    }

    // ---- layer 3: 30 -> 20, BN + ReLU ----
    v2f D[ROWS][10];
#pragma unroll
    for (int j = 0; j < 10; ++j) {
      const v2f bb = {b3[2 * j], b3[2 * j + 1]};
#pragma unroll
      for (int r = 0; r < ROWS; ++r) D[r][j] = bb;
    }
#pragma unroll
    for (int k = 0; k < 30; ++k) {
#pragma unroll
      for (int j = 0; j < 10; ++j) {
        const v2f w = {W3[k * 20 + 2 * j], W3[k * 20 + 2 * j + 1]};
#pragma unroll
        for (int r = 0; r < ROWS; ++r) {
          const v2f hk2 = {a2[r][k], a2[r][k]};
          D[r][j] = __builtin_elementwise_fma(hk2, w, D[r][j]);
        }
      }
    }
    float a3[ROWS][20];
#pragma unroll
    for (int j = 0; j < 10; ++j) {
      const float s0 = g3[2 * j + 0] * rden, s1 = g3[2 * j + 1] * rden;
      const float o0 = be3[2 * j + 0],       o1 = be3[2 * j + 1];
#pragma unroll
      for (int r = 0; r < ROWS; ++r) {
        a3[r][2 * j + 0] = fmaxf(fmaf(D[r][j].x, s0, o0), 0.f);
        a3[r][2 * j + 1] = fmaxf(fmaf(D[r][j].y, s1, o1), 0.f);
      }
    }

    // ---- layer 4: 20 -> 15, ReLU (no BN); 7 pairs + 1 scalar tail ----
    v2f E[ROWS][7];
    float e14[ROWS];
#pragma unroll
    for (int j = 0; j < 7; ++j) {
      const v2f bb = {b4[2 * j], b4[2 * j + 1]};
#pragma unroll
      for (int r = 0; r < ROWS; ++r) E[r][j] = bb;
    }
#pragma unroll
    for (int r = 0; r < ROWS; ++r) e14[r] = b4[14];
#pragma unroll
    for (int k = 0; k < 20; ++k) {
#pragma unroll
      for (int j = 0; j < 7; ++j) {
        const v2f w = {W4[k * 15 + 2 * j], W4[k * 15 + 2 * j + 1]};
#pragma unroll
        for (int r = 0; r < ROWS; ++r) {
          const v2f hk2 = {a3[r][k], a3[r][k]};
          E[r][j] = __builtin_elementwise_fma(hk2, w, E[r][j]);
        }
      }
      const float w14 = W4[k * 15 + 14];
#pragma unroll
      for (int r = 0; r < ROWS; ++r) e14[r] = fmaf(a3[r][k], w14, e14[r]);
    }
    float a4[ROWS][15];
#pragma unroll
    for (int r = 0; r < ROWS; ++r) {
#pragma unroll
      for (int j = 0; j < 7; ++j) {
        a4[r][2 * j + 0] = fmaxf(E[r][j].x, 0.f);
        a4[r][2 * j + 1] = fmaxf(E[r][j].y, 0.f);
      }
      a4[r][14] = fmaxf(e14[r], 0.f);
    }

    // ---- layer 5: 15 -> 8, sigmoid ----
    v2f P[ROWS][4];
#pragma unroll
    for (int j = 0; j < 4; ++j) {
      const v2f bb = {b5[2 * j], b5[2 * j + 1]};
#pragma unroll
      for (int r = 0; r < ROWS; ++r) P[r][j] = bb;
    }
#pragma unroll
    for (int k = 0; k < 15; ++k) {
#pragma unroll
      for (int j = 0; j < 4; ++j) {
        const v2f w = {W5[k * 8 + 2 * j], W5[k * 8 + 2 * j + 1]};
#pragma unroll
        for (int r = 0; r < ROWS; ++r) {
          const v2f hk2 = {a4[r][k], a4[r][k]};
          P[r][j] = __builtin_elementwise_fma(hk2, w, P[r][j]);
        }
      }
    }

    // ---- sigmoid + bernoulli(1-p) via partitionable threefry + flag ----
#pragma unroll
    for (int r = 0; r < ROWS; ++r) {
      if (!act[r]) continue;
      const int rb = row0 + r * THREADS;
      float p[8];
#pragma unroll
      for (int j = 0; j < 4; ++j) {
        p[2 * j + 0] = 1.f / (1.f + __expf(-P[r][j].x));
        p[2 * j + 1] = 1.f / (1.f + __expf(-P[r][j].y));
      }
      bool need = false;
      float prod = 1.f;
      float ch[8];
#pragma unroll
      for (int w = 0; w < 8; ++w) {
        unsigned j = 8u * (unsigned)rb + (unsigned)w, o0, o1;
        tf2x32(0u, j, o0, o1);
        unsigned bits = o0 ^ o1;
        float u = __uint_as_float(0x3F800000u | (bits >> 9)) - 1.f;
        float thr = 1.f - p[w];
        bool choice = u < thr;
        need = need || (fabsf(u - thr) < P_MARGIN);
        ch[w] = choice ? 0.f : 1.f;
        prod *= choice ? thr : p[w];
      }
      if (need) {
        unsigned i = atomicAdd(&s_cnt, 1u);
        if (i < FIXCAP) s_rows[i] = (unsigned)rb;
      }
      float4* oc = reinterpret_cast<float4*>(out_chosen) + (size_t)rb * 2;
      oc[0] = make_float4(ch[0], ch[1], ch[2], ch[3]);
      oc[1] = make_float4(ch[4], ch[5], ch[6], ch[7]);
      out_logp[rb] = __logf(prod);
    }
  }

  // ---- block-cooperative fp64 repair of flagged rows (overwrites) ----
  __syncthreads();  // also drains this block's fp32 stores (vmcnt at barrier)
  unsigned cnt = s_cnt;
  if (cnt > FIXCAP) cnt = FIXCAP;
  if (cnt == 0) return;

  const double denom = sqrt(1.0 + 1e-5);
  for (unsigned r = 0; r < cnt; ++r) {  // cnt is block-uniform
    const int rb = (int)s_rows[r];

    if (t < 32) sA[t] = (double)events[(size_t)rb * 32 + t];
    __syncthreads();

    double v = 0.0;
    if (t < 50) {
#pragma unroll
      for (int k = 0; k < 32; ++k) v = fma(sA[k], (double)W1[k * 50 + t], v);
      v += (double)b1[t];
      v = v * ((double)g1[t] / denom) + (double)be1[t];
      v = v > 0.0 ? v : 0.0;
    }
    __syncthreads();
    if (t < 50) sB[t] = v;
    __syncthreads();

    v = 0.0;
    if (t < 30) {
#pragma unroll
      for (int k = 0; k < 50; ++k) v = fma(sB[k], (double)W2[k * 30 + t], v);
      v += (double)b2[t];
      v = v * ((double)g2[t] / denom) + (double)be2[t];
      v = v > 0.0 ? v : 0.0;
    }
    __syncthreads();
    if (t < 30) sA[t] = v;
    __syncthreads();

    v = 0.0;
    if (t < 20) {
#pragma unroll
      for (int k = 0; k < 30; ++k) v = fma(sA[k], (double)W3[k * 20 + t], v);
      v += (double)b3[t];
      v = v * ((double)g3[t] / denom) + (double)be3[t];
      v = v > 0.0 ? v : 0.0;
    }
    __syncthreads();
    if (t < 20) sB[t] = v;
    __syncthreads();

    v = 0.0;
    if (t < 15) {
#pragma unroll
      for (int k = 0; k < 20; ++k) v = fma(sB[k], (double)W4[k * 15 + t], v);
      v += (double)b4[t];
      v = v > 0.0 ? v : 0.0;
    }
    __syncthreads();
    if (t < 15) sA[t] = v;
    __syncthreads();

    if (t < 8) {
      v = 0.0;
#pragma unroll
      for (int k = 0; k < 15; ++k) v = fma(sA[k], (double)W5[k * 8 + t], v);
      v += (double)b5[t];
      double p = 1.0 / (1.0 + exp(-v));
      unsigned j = 8u * (unsigned)rb + (unsigned)t, o0, o1;
      tf2x32(0u, j, o0, o1);
      unsigned bits = o0 ^ o1;
      float u = __uint_as_float(0x3F800000u | (bits >> 9)) - 1.f;
      double thr = 1.0 - p;
      bool choice = ((double)u < thr);
      out_chosen[(size_t)rb * 8 + t] = choice ? 0.f : 1.f;
      sF[t] = choice ? thr : p;
    }
    __syncthreads();
    if (t == 0) {
      double prod = 1.0;
      for (int w = 0; w < 8; ++w) prod *= sF[w];
      out_logp[rb] = (float)log(prod);
    }
    __syncthreads();
  }
}

extern "C" void kernel_launch(void* const* d_in, const int* in_sizes, int n_in,
                              void* d_out, int out_size, void* d_ws, size_t ws_size,
                              hipStream_t stream) {
  const float* events = (const float*)d_in[0];
  const float* W1  = (const float*)d_in[1];
  const float* b1  = (const float*)d_in[2];
  const float* g1  = (const float*)d_in[3];
  const float* be1 = (const float*)d_in[4];
  const float* W2  = (const float*)d_in[5];
  const float* b2  = (const float*)d_in[6];
  const float* g2  = (const float*)d_in[7];
  const float* be2 = (const float*)d_in[8];
  const float* W3  = (const float*)d_in[9];
  const float* b3  = (const float*)d_in[10];
  const float* g3  = (const float*)d_in[11];
  const float* be3 = (const float*)d_in[12];
  const float* W4  = (const float*)d_in[13];
  const float* b4  = (const float*)d_in[14];
  const float* W5  = (const float*)d_in[15];
  const float* b5  = (const float*)d_in[16];

  const int B = in_sizes[0] / 32;  // 524288
  float* out = (float*)d_out;
  float* out_chosen = out;                   // (B, 8)
  float* out_logp   = out + (size_t)B * 8;   // (B,)

  const int rows_per_block = THREADS * ROWS;
  const int blocks = (B + rows_per_block - 1) / rows_per_block;
  hipLaunchKernelGGL(wtf_kernel, dim3(blocks), dim3(THREADS), 0, stream,
                     events, W1, b1, g1, be1, W2, b2, g2, be2,
                     W3, b3, g3, be3, W4, b4, W5, b5,
                     out_chosen, out_logp, B);
}

// Round 4
// 239.405 us; speedup vs baseline: 2.0351x; 2.0351x over previous
//
#include <hip/hip_runtime.h>
#include <math.h>

#define THREADS 256
// fp32-vs-fp64 p error is <~4e-6 worst case (incl. v_exp_f32); 1e-4 margin
// is ~25x safety.
#define P_MARGIN 1e-4f
#define FIXCAP 32

// LDS weight-pool layout (dword offsets). Total 4443 floats = 17772 B.
#define OW1 0      // 1600
#define OW2 1600   // 1500
#define OW3 3100   // 600
#define OW4 3700   // 300
#define OW5 4000   // 120
#define OB1 4120   // 50
#define OS1 4170   // 50 (g1*rden folded)
#define OE1 4220   // 50
#define OB2 4270   // 30
#define OS2 4300   // 30
#define OE2 4330   // 30
#define OB3 4360   // 20
#define OS3 4380   // 20
#define OE3 4400   // 20
#define OB4 4420   // 15
#define OB5 4435   // 8
#define WPOOL 4443

typedef float v2f __attribute__((ext_vector_type(2)));

// Exact JAX threefry2x32 (20 rounds, key schedule every 4), key = (0, 42).
// Partitionable stream: bits[j] = o0 ^ o1 of threefry2x32(key, 0, j).
__device__ __forceinline__ void tf2x32(unsigned x0, unsigned x1,
                                       unsigned &o0, unsigned &o1) {
  const unsigned k0 = 0u;
  const unsigned k1 = 42u;
  const unsigned k2 = 0x1BD11BDAu ^ k0 ^ k1;
  x0 += k0; x1 += k1;
#define TF_R(r) { x0 += x1; x1 = (x1 << (r)) | (x1 >> (32 - (r))); x1 ^= x0; }
  TF_R(13) TF_R(15) TF_R(26) TF_R(6)
  x0 += k1; x1 += k2 + 1u;
  TF_R(17) TF_R(29) TF_R(16) TF_R(24)
  x0 += k2; x1 += k0 + 2u;
  TF_R(13) TF_R(15) TF_R(26) TF_R(6)
  x0 += k0; x1 += k1 + 3u;
  TF_R(17) TF_R(29) TF_R(16) TF_R(24)
  x0 += k1; x1 += k2 + 4u;
  TF_R(13) TF_R(15) TF_R(26) TF_R(6)
  x0 += k2; x1 += k0 + 5u;
#undef TF_R
  o0 = x0; o1 = x1;
}

// Single fused kernel. R3 (resubmit; prior bench was an infra failure):
// weights delivered from LDS, not s_load.
//  - R1 diagnosis: weights streamed via s_load with SGPR file maxed (112) ->
//    ~1 k-step of lookahead vs ~100cy K$ latency -> VALUBusy 25%. R2's
//    register row-tiling fix spilled (allocator caps at 128 VGPR). Instead:
//    stage all 4443 param dwords in LDS once per block; inner loops read
//    them as wave-broadcast ds_reads (all lanes same addr, conflict-free),
//    which the compiler batches under lgkmcnt -- latency covered by
//    batching, no SGPR pressure.
//  - fp32 fast path numerics bit-identical to R1 (same IEEE ops/order;
//    g*rden folded at staging is the same fp32 multiply).
//  - rows whose bernoulli comparison is within P_MARGIN of the threshold go
//    to a per-block LDS list; after a barrier the block cooperatively re-runs
//    them in fp64 (lane=neuron, global weights) and overwrites. Expected
//    ~0.4 flagged rows/block; cap 32.
__global__ __launch_bounds__(THREADS, 2)
void wtf_kernel(const float* __restrict__ events,
                const float* __restrict__ W1, const float* __restrict__ b1,
                const float* __restrict__ g1, const float* __restrict__ be1,
                const float* __restrict__ W2, const float* __restrict__ b2,
                const float* __restrict__ g2, const float* __restrict__ be2,
                const float* __restrict__ W3, const float* __restrict__ b3,
                const float* __restrict__ g3, const float* __restrict__ be3,
                const float* __restrict__ W4, const float* __restrict__ b4,
                const float* __restrict__ W5, const float* __restrict__ b5,
                float* __restrict__ out_chosen,
                float* __restrict__ out_logp,
                int B) {
  __shared__ float sW[WPOOL];
  __shared__ unsigned s_cnt;
  __shared__ unsigned s_rows[FIXCAP];
  __shared__ double sA[64];
  __shared__ double sB[64];
  __shared__ double sF[8];

  const int t = threadIdx.x;
  const float rden = (float)(1.0 / sqrt(1.0 + 1e-5));

  // ---- stage params into LDS (vectorized; W sizes are all %4==0) ----
  if (t == 0) s_cnt = 0;
  {
    float4* dW = reinterpret_cast<float4*>(sW);
    const float4* gW1 = reinterpret_cast<const float4*>(W1);
    for (int i = t; i < 400; i += THREADS) dW[i] = gW1[i];
    const float4* gW2 = reinterpret_cast<const float4*>(W2);
    for (int i = t; i < 375; i += THREADS) dW[400 + i] = gW2[i];
    const float4* gW3 = reinterpret_cast<const float4*>(W3);
    for (int i = t; i < 150; i += THREADS) dW[775 + i] = gW3[i];
    const float4* gW4 = reinterpret_cast<const float4*>(W4);
    for (int i = t; i < 75; i += THREADS) dW[925 + i] = gW4[i];
    const float4* gW5 = reinterpret_cast<const float4*>(W5);
    for (int i = t; i < 30; i += THREADS) dW[1000 + i] = gW5[i];
    if (t < 50) { sW[OB1 + t] = b1[t]; sW[OS1 + t] = g1[t] * rden; sW[OE1 + t] = be1[t]; }
    else if (t >= 64 && t < 94)  { int i = t - 64;  sW[OB2 + i] = b2[i];  sW[OS2 + i] = g2[i] * rden; sW[OE2 + i] = be2[i]; }
    else if (t >= 128 && t < 148) { int i = t - 128; sW[OB3 + i] = b3[i];  sW[OS3 + i] = g3[i] * rden; sW[OE3 + i] = be3[i]; }
    else if (t >= 192 && t < 207) { int i = t - 192; sW[OB4 + i] = b4[i]; }
    else if (t >= 224 && t < 232) { int i = t - 224; sW[OB5 + i] = b5[i]; }
  }
  __syncthreads();

  const int b = blockIdx.x * THREADS + t;
  const bool active = (b < B);

  if (active) {
    float x[32];
    const float4* ev4 = reinterpret_cast<const float4*>(events) + (size_t)b * 8;
#pragma unroll
    for (int q = 0; q < 8; ++q) {
      float4 v = ev4[q];
      x[4 * q + 0] = v.x; x[4 * q + 1] = v.y; x[4 * q + 2] = v.z; x[4 * q + 3] = v.w;
    }

    // ---- layer 1: 32 -> 50, BN + ReLU (packed f32x2 accumulators) ----
    v2f A[25];
#pragma unroll
    for (int j = 0; j < 25; ++j) A[j] = v2f{sW[OB1 + 2 * j], sW[OB1 + 2 * j + 1]};
#pragma unroll
    for (int k = 0; k < 32; ++k) {
      const v2f xk2 = {x[k], x[k]};
#pragma unroll
      for (int j = 0; j < 25; ++j) {
        v2f w = {sW[OW1 + k * 50 + 2 * j], sW[OW1 + k * 50 + 2 * j + 1]};
        A[j] = __builtin_elementwise_fma(xk2, w, A[j]);
      }
    }
    float a1[50];
#pragma unroll
    for (int j = 0; j < 25; ++j) {
      a1[2 * j + 0] = fmaxf(fmaf(A[j].x, sW[OS1 + 2 * j + 0], sW[OE1 + 2 * j + 0]), 0.f);
      a1[2 * j + 1] = fmaxf(fmaf(A[j].y, sW[OS1 + 2 * j + 1], sW[OE1 + 2 * j + 1]), 0.f);
    }

    // ---- layer 2: 50 -> 30, BN + ReLU ----
    v2f C[15];
#pragma unroll
    for (int j = 0; j < 15; ++j) C[j] = v2f{sW[OB2 + 2 * j], sW[OB2 + 2 * j + 1]};
#pragma unroll
    for (int k = 0; k < 50; ++k) {
      const v2f hk2 = {a1[k], a1[k]};
#pragma unroll
      for (int j = 0; j < 15; ++j) {
        v2f w = {sW[OW2 + k * 30 + 2 * j], sW[OW2 + k * 30 + 2 * j + 1]};
        C[j] = __builtin_elementwise_fma(hk2, w, C[j]);
      }
    }
    float a2[30];
#pragma unroll
    for (int j = 0; j < 15; ++j) {
      a2[2 * j + 0] = fmaxf(fmaf(C[j].x, sW[OS2 + 2 * j + 0], sW[OE2 + 2 * j + 0]), 0.f);
      a2[2 * j + 1] = fmaxf(fmaf(C[j].y, sW[OS2 + 2 * j + 1], sW[OE2 + 2 * j + 1]), 0.f);
    }

    // ---- layer 3: 30 -> 20, BN + ReLU ----
    v2f D[10];
#pragma unroll
    for (int j = 0; j < 10; ++j) D[j] = v2f{sW[OB3 + 2 * j], sW[OB3 + 2 * j + 1]};
#pragma unroll
    for (int k = 0; k < 30; ++k) {
      const v2f hk2 = {a2[k], a2[k]};
#pragma unroll
      for (int j = 0; j < 10; ++j) {
        v2f w = {sW[OW3 + k * 20 + 2 * j], sW[OW3 + k * 20 + 2 * j + 1]};
        D[j] = __builtin_elementwise_fma(hk2, w, D[j]);
      }
    }
    float a3[20];
#pragma unroll
    for (int j = 0; j < 10; ++j) {
      a3[2 * j + 0] = fmaxf(fmaf(D[j].x, sW[OS3 + 2 * j + 0], sW[OE3 + 2 * j + 0]), 0.f);
      a3[2 * j + 1] = fmaxf(fmaf(D[j].y, sW[OS3 + 2 * j + 1], sW[OE3 + 2 * j + 1]), 0.f);
    }

    // ---- layer 4: 20 -> 15, ReLU (no BN); 7 pairs + 1 scalar tail ----
    v2f E[7];
    float e14 = sW[OB4 + 14];
#pragma unroll
    for (int j = 0; j < 7; ++j) E[j] = v2f{sW[OB4 + 2 * j], sW[OB4 + 2 * j + 1]};
#pragma unroll
    for (int k = 0; k < 20; ++k) {
      const float hk = a3[k];
      const v2f hk2 = {hk, hk};
#pragma unroll
      for (int j = 0; j < 7; ++j) {
        v2f w = {sW[OW4 + k * 15 + 2 * j], sW[OW4 + k * 15 + 2 * j + 1]};
        E[j] = __builtin_elementwise_fma(hk2, w, E[j]);
      }
      e14 = fmaf(hk, sW[OW4 + k * 15 + 14], e14);
    }
    float a4[15];
#pragma unroll
    for (int j = 0; j < 7; ++j) {
      a4[2 * j + 0] = fmaxf(E[j].x, 0.f);
      a4[2 * j + 1] = fmaxf(E[j].y, 0.f);
    }
    a4[14] = fmaxf(e14, 0.f);

    // ---- layer 5: 15 -> 8, sigmoid ----
    v2f P[4];
#pragma unroll
    for (int j = 0; j < 4; ++j) P[j] = v2f{sW[OB5 + 2 * j], sW[OB5 + 2 * j + 1]};
#pragma unroll
    for (int k = 0; k < 15; ++k) {
      const v2f hk2 = {a4[k], a4[k]};
#pragma unroll
      for (int j = 0; j < 4; ++j) {
        v2f w = {sW[OW5 + k * 8 + 2 * j], sW[OW5 + k * 8 + 2 * j + 1]};
        P[j] = __builtin_elementwise_fma(hk2, w, P[j]);
      }
    }
    float p[8];
#pragma unroll
    for (int j = 0; j < 4; ++j) {
      p[2 * j + 0] = 1.f / (1.f + __expf(-P[j].x));
      p[2 * j + 1] = 1.f / (1.f + __expf(-P[j].y));
    }

    // ---- bernoulli(1-p) via partitionable threefry + margin flag ----
    bool need = false;
    float prod = 1.f;
    float ch[8];
#pragma unroll
    for (int w = 0; w < 8; ++w) {
      unsigned j = 8u * (unsigned)b + (unsigned)w, o0, o1;
      tf2x32(0u, j, o0, o1);
      unsigned bits = o0 ^ o1;
      float u = __uint_as_float(0x3F800000u | (bits >> 9)) - 1.f;
      float thr = 1.f - p[w];
      bool choice = u < thr;
      need = need || (fabsf(u - thr) < P_MARGIN);
      ch[w] = choice ? 0.f : 1.f;
      prod *= choice ? thr : p[w];
    }
    if (need) {
      unsigned i = atomicAdd(&s_cnt, 1u);
      if (i < FIXCAP) s_rows[i] = (unsigned)b;
    }

    float4* oc = reinterpret_cast<float4*>(out_chosen) + (size_t)b * 2;
    oc[0] = make_float4(ch[0], ch[1], ch[2], ch[3]);
    oc[1] = make_float4(ch[4], ch[5], ch[6], ch[7]);
    out_logp[b] = __logf(prod);
  }

  // ---- block-cooperative fp64 repair of flagged rows (overwrites) ----
  __syncthreads();  // also drains this block's fp32 stores (vmcnt at barrier)
  unsigned cnt = s_cnt;
  if (cnt > FIXCAP) cnt = FIXCAP;
  if (cnt == 0) return;

  const double denom = sqrt(1.0 + 1e-5);
  for (unsigned r = 0; r < cnt; ++r) {  // cnt is block-uniform
    const int rb = (int)s_rows[r];

    if (t < 32) sA[t] = (double)events[(size_t)rb * 32 + t];
    __syncthreads();

    double v = 0.0;
    if (t < 50) {
#pragma unroll
      for (int k = 0; k < 32; ++k) v = fma(sA[k], (double)W1[k * 50 + t], v);
      v += (double)b1[t];
      v = v * ((double)g1[t] / denom) + (double)be1[t];
      v = v > 0.0 ? v : 0.0;
    }
    __syncthreads();
    if (t < 50) sB[t] = v;
    __syncthreads();

    v = 0.0;
    if (t < 30) {
#pragma unroll
      for (int k = 0; k < 50; ++k) v = fma(sB[k], (double)W2[k * 30 + t], v);
      v += (double)b2[t];
      v = v * ((double)g2[t] / denom) + (double)be2[t];
      v = v > 0.0 ? v : 0.0;
    }
    __syncthreads();
    if (t < 30) sA[t] = v;
    __syncthreads();

    v = 0.0;
    if (t < 20) {
#pragma unroll
      for (int k = 0; k < 30; ++k) v = fma(sA[k], (double)W3[k * 20 + t], v);
      v += (double)b3[t];
      v = v * ((double)g3[t] / denom) + (double)be3[t];
      v = v > 0.0 ? v : 0.0;
    }
    __syncthreads();
    if (t < 20) sB[t] = v;
    __syncthreads();

    v = 0.0;
    if (t < 15) {
#pragma unroll
      for (int k = 0; k < 20; ++k) v = fma(sB[k], (double)W4[k * 15 + t], v);
      v += (double)b4[t];
      v = v > 0.0 ? v : 0.0;
    }
    __syncthreads();
    if (t < 15) sA[t] = v;
    __syncthreads();

    if (t < 8) {
      v = 0.0;
#pragma unroll
      for (int k = 0; k < 15; ++k) v = fma(sA[k], (double)W5[k * 8 + t], v);
      v += (double)b5[t];
      double p = 1.0 / (1.0 + exp(-v));
      unsigned j = 8u * (unsigned)rb + (unsigned)t, o0, o1;
      tf2x32(0u, j, o0, o1);
      unsigned bits = o0 ^ o1;
      float u = __uint_as_float(0x3F800000u | (bits >> 9)) - 1.f;
      double thr = 1.0 - p;
      bool choice = ((double)u < thr);
      out_chosen[(size_t)rb * 8 + t] = choice ? 0.f : 1.f;
      sF[t] = choice ? thr : p;
    }
    __syncthreads();
    if (t == 0) {
      double prod = 1.0;
      for (int w = 0; w < 8; ++w) prod *= sF[w];
      out_logp[rb] = (float)log(prod);
    }
    __syncthreads();
  }
}

extern "C" void kernel_launch(void* const* d_in, const int* in_sizes, int n_in,
                              void* d_out, int out_size, void* d_ws, size_t ws_size,
                              hipStream_t stream) {
  const float* events = (const float*)d_in[0];
  const float* W1  = (const float*)d_in[1];
  const float* b1  = (const float*)d_in[2];
  const float* g1  = (const float*)d_in[3];
  const float* be1 = (const float*)d_in[4];
  const float* W2  = (const float*)d_in[5];
  const float* b2  = (const float*)d_in[6];
  const float* g2  = (const float*)d_in[7];
  const float* be2 = (const float*)d_in[8];
  const float* W3  = (const float*)d_in[9];
  const float* b3  = (const float*)d_in[10];
  const float* g3  = (const float*)d_in[11];
  const float* be3 = (const float*)d_in[12];
  const float* W4  = (const float*)d_in[13];
  const float* b4  = (const float*)d_in[14];
  const float* W5  = (const float*)d_in[15];
  const float* b5  = (const float*)d_in[16];

  const int B = in_sizes[0] / 32;  // 524288
  float* out = (float*)d_out;
  float* out_chosen = out;                   // (B, 8)
  float* out_logp   = out + (size_t)B * 8;   // (B,)

  const int blocks = (B + THREADS - 1) / THREADS;
  hipLaunchKernelGGL(wtf_kernel, dim3(blocks), dim3(THREADS), 0, stream,
                     events, W1, b1, g1, be1, W2, b2, g2, be2,
                     W3, b3, g3, be3, W4, b4, W5, b5,
                     out_chosen, out_logp, B);
}

// Round 5
// 230.864 us; speedup vs baseline: 2.1104x; 1.0370x over previous
//
#include <hip/hip_runtime.h>
#include <math.h>

#define THREADS 256
#define TPW 8                  // 16-row tiles per wave
#define ROWS_PER_BLOCK 512     // 4 waves * TPW * 16
// bf16x3 (RTN) MFMA p-error <~2e-5 worst case; 2e-4 margin is ~10x safety.
#define P_MARGIN 2e-4f
#define FIXCAP 64

typedef float f32x4 __attribute__((ext_vector_type(4)));
typedef short short8 __attribute__((ext_vector_type(8)));
union Frag { unsigned u[4]; short8 s; };

// ---- LDS dword offsets ----
// Weight fragments (packed bf16x2), per layer:
//   entry dword = FRL + ((kt*NT + nt)*2 + hilo)*256 + lane*4 + d
//   lane = 8*? no: lane = (k-subgroup g)*16 + (col&15); dword d holds k-offsets {2d, 2d+1}
#define FR1 0       // L1: 32x64  (kt1,nt4) -> 8*256
#define FR2 2048    // L2: 64x32  (kt2,nt2) -> 8*256
#define FR3 4096    // L3: 32x32  (kt1,nt2) -> 4*256
#define FR4 5120    // L4: 32x16  -> 2*256
#define FR5 5632    // L5: 32x16  -> 2*256
#define VB1 6144    // bias1 (64, zero-padded)
#define VS1 6208    // g1*rden
#define VE1 6272
#define VB2 6336    // (32)
#define VS2 6368
#define VE2 6400
#define VB3 6432
#define VS3 6464
#define VE3 6496
#define VB4 6528    // (16)
#define VB5 6544    // (16)
#define ZEND 6560
#define ACT 6560    // per-wave activation tile [feature(64)][row(16)] stride 17 -> 1088 dw
#define PT  10912   // per-wave logit tile [row(16)][col(8)] stride 9 -> 144 dw
#define WPOOL 11488 // 45952 B

// Exact JAX threefry2x32 (20 rounds, key schedule every 4), key = (0, 42).
__device__ __forceinline__ void tf2x32(unsigned x0, unsigned x1,
                                       unsigned &o0, unsigned &o1) {
  const unsigned k0 = 0u;
  const unsigned k1 = 42u;
  const unsigned k2 = 0x1BD11BDAu ^ k0 ^ k1;
  x0 += k0; x1 += k1;
#define TF_R(r) { x0 += x1; x1 = (x1 << (r)) | (x1 >> (32 - (r))); x1 ^= x0; }
  TF_R(13) TF_R(15) TF_R(26) TF_R(6)
  x0 += k1; x1 += k2 + 1u;
  TF_R(17) TF_R(29) TF_R(16) TF_R(24)
  x0 += k2; x1 += k0 + 2u;
  TF_R(13) TF_R(15) TF_R(26) TF_R(6)
  x0 += k0; x1 += k1 + 3u;
  TF_R(17) TF_R(29) TF_R(16) TF_R(24)
  x0 += k1; x1 += k2 + 4u;
  TF_R(13) TF_R(15) TF_R(26) TF_R(6)
  x0 += k2; x1 += k0 + 5u;
#undef TF_R
  o0 = x0; o1 = x1;
}

// bf16 round-to-nearest-even, result in top 16 bits (low 16 zero)
__device__ __forceinline__ unsigned rtnb(float v) {
  unsigned b = __float_as_uint(v);
  return (b + 0x7FFFu + ((b >> 16) & 1u)) & 0xFFFF0000u;
}

// v_cvt_pk_bf16_f32: dst = {bf16(a) low16, bf16(b) high16}, RTNE
__device__ __forceinline__ unsigned cvtpk(float a, float b) {
  unsigned r;
  asm("v_cvt_pk_bf16_f32 %0, %1, %2" : "=v"(r) : "v"(a), "v"(b));
  return r;
}

// Split 8 f32 (k-offsets 0..7) into hi/lo bf16x8 fragments (dword d = {2d,2d+1})
__device__ __forceinline__ void pack8(const float f[8], short8 &H, short8 &L) {
  Frag h, l;
#pragma unroll
  for (int d = 0; d < 4; ++d) {
    unsigned hd = cvtpk(f[2 * d], f[2 * d + 1]);
    h.u[d] = hd;
    float r0 = f[2 * d]     - __uint_as_float(hd << 16);
    float r1 = f[2 * d + 1] - __uint_as_float(hd & 0xFFFF0000u);
    l.u[d] = cvtpk(r0, r1);
  }
  H = h.s; L = l.s;
}

__device__ __forceinline__ f32x4 mfma16(short8 a, short8 b, f32x4 c) {
  return __builtin_amdgcn_mfma_f32_16x16x32_bf16(a, b, c, 0, 0, 0);
}

__device__ __forceinline__ short8 ldfrag(const float *sW, int dwoff) {
  return *reinterpret_cast<const short8 *>(sW + dwoff);
}

// Stage one weight matrix into B-fragment LDS layout (hi+lo bf16 halves).
// Zero padding comes from the pre-zeroed region (untouched slots stay 0).
template <int K, int N, int NT, int FB>
__device__ __forceinline__ void stage_layer(const float *__restrict__ W,
                                            float *sW, int t) {
  for (int i = t; i < K * N; i += THREADS) {
    int k = i / N, c = i - k * N;
    float v = W[i];
    unsigned hb = rtnb(v);
    float lov = v - __uint_as_float(hb);
    unsigned lb = rtnb(lov);
    int kt = k >> 5, gg = (k >> 3) & 3, d = (k >> 1) & 3, par = k & 1;
    int nt = c >> 4, lane = gg * 16 + (c & 15);
    int combo = kt * NT + nt;
    int dwhi = FB + (combo * 2 + 0) * 256 + lane * 4 + d;
    unsigned short *hp = reinterpret_cast<unsigned short *>(sW);
    hp[2 * dwhi + par] = (unsigned short)(hb >> 16);
    hp[2 * (dwhi + 256) + par] = (unsigned short)(lb >> 16);
  }
}

// Read A-fragment (rows=lane&15, k = kbase + (lane>>4)*8 + e) from act tile.
__device__ __forceinline__ void loadA(const float *actw, int kbase, int c,
                                      int g, short8 &H, short8 &L) {
  float f[8];
#pragma unroll
  for (int e = 0; e < 8; ++e) f[e] = actw[(kbase + g * 8 + e) * 17 + c];
  pack8(f, H, L);
}

__global__ __launch_bounds__(THREADS, 2)
void wtf_kernel(const float* __restrict__ events,
                const float* __restrict__ W1, const float* __restrict__ b1,
                const float* __restrict__ g1, const float* __restrict__ be1,
                const float* __restrict__ W2, const float* __restrict__ b2,
                const float* __restrict__ g2, const float* __restrict__ be2,
                const float* __restrict__ W3, const float* __restrict__ b3,
                const float* __restrict__ g3, const float* __restrict__ be3,
                const float* __restrict__ W4, const float* __restrict__ b4,
                const float* __restrict__ W5, const float* __restrict__ b5,
                float* __restrict__ out_chosen,
                float* __restrict__ out_logp,
                int B) {
  __shared__ float sW[WPOOL];
  __shared__ unsigned s_cnt;
  __shared__ unsigned s_rows[FIXCAP];
  __shared__ double sA[64];
  __shared__ double sB[64];
  __shared__ double sF[8];

  const int t = threadIdx.x;
  const float rden = (float)(1.0 / sqrt(1.0 + 1e-5));

  // ---- stage: zero frag+vec region, then pack weights as bf16 hi/lo ----
  if (t == 0) s_cnt = 0;
  for (int i = t; i < ZEND; i += THREADS) sW[i] = 0.f;
  __syncthreads();
  stage_layer<32, 50, 4, FR1>(W1, sW, t);
  stage_layer<50, 30, 2, FR2>(W2, sW, t);
  stage_layer<30, 20, 2, FR3>(W3, sW, t);
  stage_layer<20, 15, 1, FR4>(W4, sW, t);
  stage_layer<15, 8, 1, FR5>(W5, sW, t);
  if (t < 50)                  { sW[VB1 + t] = b1[t]; sW[VS1 + t] = g1[t] * rden; sW[VE1 + t] = be1[t]; }
  else if (t >= 64 && t < 94)  { int i = t - 64;  sW[VB2 + i] = b2[i]; sW[VS2 + i] = g2[i] * rden; sW[VE2 + i] = be2[i]; }
  else if (t >= 128 && t < 148){ int i = t - 128; sW[VB3 + i] = b3[i]; sW[VS3 + i] = g3[i] * rden; sW[VE3 + i] = be3[i]; }
  else if (t >= 192 && t < 207){ sW[VB4 + (t - 192)] = b4[t - 192]; }
  else if (t >= 224 && t < 232){ sW[VB5 + (t - 224)] = b5[t - 224]; }
  __syncthreads();

  const int w = t >> 6, lane = t & 63;
  const int c = lane & 15, g = lane >> 4;
  float *actw = sW + ACT + w * 1088;  // [feature][row], stride 17
  float *ptw  = sW + PT  + w * 144;   // [row][col], stride 9

#pragma unroll 1
  for (int tt = 0; tt < TPW; ++tt) {
    const int r0 = blockIdx.x * ROWS_PER_BLOCK + w * (TPW * 16) + tt * 16;

    // ---- X fragment straight from global: row = r0+c, k = g*8+e ----
    const float4 *xr = reinterpret_cast<const float4 *>(
        events + (size_t)(r0 + c) * 32 + g * 8);
    float4 xa = xr[0], xb = xr[1];
    float xf[8] = {xa.x, xa.y, xa.z, xa.w, xb.x, xb.y, xb.z, xb.w};
    short8 Xh, Xl; pack8(xf, Xh, Xl);

    // ---- L1: (16x32)x(32x64), BN+ReLU -> act[0..63] ----
    {
      f32x4 acc[4];
#pragma unroll
      for (int nt = 0; nt < 4; ++nt) {
        float bb = sW[VB1 + nt * 16 + c];
        f32x4 ci = {bb, bb, bb, bb};
        short8 bh = ldfrag(sW, FR1 + (nt * 2 + 0) * 256 + lane * 4);
        short8 bl = ldfrag(sW, FR1 + (nt * 2 + 1) * 256 + lane * 4);
        ci = mfma16(Xl, bh, ci);
        ci = mfma16(Xh, bl, ci);
        acc[nt] = mfma16(Xh, bh, ci);
      }
#pragma unroll
      for (int nt = 0; nt < 4; ++nt) {
        float sc = sW[VS1 + nt * 16 + c], of = sW[VE1 + nt * 16 + c];
#pragma unroll
        for (int r = 0; r < 4; ++r)
          actw[(nt * 16 + c) * 17 + g * 4 + r] =
              fmaxf(fmaf(acc[nt][r], sc, of), 0.f);
      }
    }

    // ---- L2: K=64 (2 kt), N=32 (2 nt), BN+ReLU -> act[0..31] ----
    {
      f32x4 acc[2];
#pragma unroll
      for (int nt = 0; nt < 2; ++nt) {
        float bb = sW[VB2 + nt * 16 + c];
        acc[nt] = f32x4{bb, bb, bb, bb};
      }
#pragma unroll
      for (int kt = 0; kt < 2; ++kt) {
        short8 Ah, Al; loadA(actw, kt * 32, c, g, Ah, Al);
#pragma unroll
        for (int nt = 0; nt < 2; ++nt) {
          short8 bh = ldfrag(sW, FR2 + ((kt * 2 + nt) * 2 + 0) * 256 + lane * 4);
          short8 bl = ldfrag(sW, FR2 + ((kt * 2 + nt) * 2 + 1) * 256 + lane * 4);
          acc[nt] = mfma16(Al, bh, acc[nt]);
          acc[nt] = mfma16(Ah, bl, acc[nt]);
          acc[nt] = mfma16(Ah, bh, acc[nt]);
        }
      }
#pragma unroll
      for (int nt = 0; nt < 2; ++nt) {
        float sc = sW[VS2 + nt * 16 + c], of = sW[VE2 + nt * 16 + c];
#pragma unroll
        for (int r = 0; r < 4; ++r)
          actw[(nt * 16 + c) * 17 + g * 4 + r] =
              fmaxf(fmaf(acc[nt][r], sc, of), 0.f);
      }
    }

    // ---- L3: K=32, N=32, BN+ReLU -> act[0..31] ----
    {
      f32x4 acc[2];
#pragma unroll
      for (int nt = 0; nt < 2; ++nt) {
        float bb = sW[VB3 + nt * 16 + c];
        acc[nt] = f32x4{bb, bb, bb, bb};
      }
      short8 Ah, Al; loadA(actw, 0, c, g, Ah, Al);
#pragma unroll
      for (int nt = 0; nt < 2; ++nt) {
        short8 bh = ldfrag(sW, FR3 + (nt * 2 + 0) * 256 + lane * 4);
        short8 bl = ldfrag(sW, FR3 + (nt * 2 + 1) * 256 + lane * 4);
        acc[nt] = mfma16(Al, bh, acc[nt]);
        acc[nt] = mfma16(Ah, bl, acc[nt]);
        acc[nt] = mfma16(Ah, bh, acc[nt]);
      }
#pragma unroll
      for (int nt = 0; nt < 2; ++nt) {
        float sc = sW[VS3 + nt * 16 + c], of = sW[VE3 + nt * 16 + c];
#pragma unroll
        for (int r = 0; r < 4; ++r)
          actw[(nt * 16 + c) * 17 + g * 4 + r] =
              fmaxf(fmaf(acc[nt][r], sc, of), 0.f);
      }
    }

    // ---- L4: K=32, N=16, ReLU -> act[0..15]; zero act[16..31] for L5 ----
    {
      float bb = sW[VB4 + c];
      f32x4 acc = {bb, bb, bb, bb};
      short8 Ah, Al; loadA(actw, 0, c, g, Ah, Al);
      short8 bh = ldfrag(sW, FR4 + 0 * 256 + lane * 4);
      short8 bl = ldfrag(sW, FR4 + 1 * 256 + lane * 4);
      acc = mfma16(Al, bh, acc);
      acc = mfma16(Ah, bl, acc);
      acc = mfma16(Ah, bh, acc);
#pragma unroll
      for (int r = 0; r < 4; ++r) {
        actw[c * 17 + g * 4 + r] = fmaxf(acc[r], 0.f);
        actw[(16 + c) * 17 + g * 4 + r] = 0.f;
      }
    }

    // ---- L5: K=32, N=16 (cols 0..7 real) -> logits to PT ----
    {
      float bb = sW[VB5 + c];
      f32x4 acc = {bb, bb, bb, bb};
      short8 Ah, Al; loadA(actw, 0, c, g, Ah, Al);
      short8 bh = ldfrag(sW, FR5 + 0 * 256 + lane * 4);
      short8 bl = ldfrag(sW, FR5 + 1 * 256 + lane * 4);
      acc = mfma16(Al, bh, acc);
      acc = mfma16(Ah, bl, acc);
      acc = mfma16(Ah, bh, acc);
      if (c < 8) {
#pragma unroll
        for (int r = 0; r < 4; ++r) ptw[(g * 4 + r) * 9 + c] = acc[r];
      }
    }

    // ---- epilogue: lane = row*4 + colpair; 2 elems/lane, all 64 useful ----
    {
      const int erow = lane >> 2, cp = lane & 3;
      const int grow = r0 + erow;
      float l0 = ptw[erow * 9 + 2 * cp];
      float l1 = ptw[erow * 9 + 2 * cp + 1];
      float p0 = 1.f / (1.f + __expf(-l0));
      float p1 = 1.f / (1.f + __expf(-l1));
      unsigned o0, o1, q0, q1;
      tf2x32(0u, 8u * (unsigned)grow + 2u * cp,      o0, o1);
      tf2x32(0u, 8u * (unsigned)grow + 2u * cp + 1u, q0, q1);
      float u0 = __uint_as_float(0x3F800000u | ((o0 ^ o1) >> 9)) - 1.f;
      float u1 = __uint_as_float(0x3F800000u | ((q0 ^ q1) >> 9)) - 1.f;
      float th0 = 1.f - p0, th1 = 1.f - p1;
      bool c0 = u0 < th0, c1 = u1 < th1;
      bool need = (fabsf(u0 - th0) < P_MARGIN) || (fabsf(u1 - th1) < P_MARGIN);
      float prod = (c0 ? th0 : p0) * (c1 ? th1 : p1);
      prod *= __shfl_xor(prod, 1);
      prod *= __shfl_xor(prod, 2);
      float2 chv = make_float2(c0 ? 0.f : 1.f, c1 ? 0.f : 1.f);
      *reinterpret_cast<float2 *>(out_chosen + (size_t)grow * 8 + 2 * cp) = chv;
      if (cp == 0) out_logp[grow] = __logf(prod);
      if (need) {
        unsigned i = atomicAdd(&s_cnt, 1u);
        if (i < FIXCAP) s_rows[i] = (unsigned)grow;
      }
    }
  }

  // ---- block-cooperative fp64 repair of flagged rows (overwrites) ----
  __syncthreads();
  unsigned cnt = s_cnt;
  if (cnt > FIXCAP) cnt = FIXCAP;
  if (cnt == 0) return;

  const double denom = sqrt(1.0 + 1e-5);
  for (unsigned r = 0; r < cnt; ++r) {  // cnt is block-uniform
    const int rb = (int)s_rows[r];

    if (t < 32) sA[t] = (double)events[(size_t)rb * 32 + t];
    __syncthreads();

    double v = 0.0;
    if (t < 50) {
#pragma unroll
      for (int k = 0; k < 32; ++k) v = fma(sA[k], (double)W1[k * 50 + t], v);
      v += (double)b1[t];
      v = v * ((double)g1[t] / denom) + (double)be1[t];
      v = v > 0.0 ? v : 0.0;
    }
    __syncthreads();
    if (t < 50) sB[t] = v;
    __syncthreads();

    v = 0.0;
    if (t < 30) {
#pragma unroll
      for (int k = 0; k < 50; ++k) v = fma(sB[k], (double)W2[k * 30 + t], v);
      v += (double)b2[t];
      v = v * ((double)g2[t] / denom) + (double)be2[t];
      v = v > 0.0 ? v : 0.0;
    }
    __syncthreads();
    if (t < 30) sA[t] = v;
    __syncthreads();

    v = 0.0;
    if (t < 20) {
#pragma unroll
      for (int k = 0; k < 30; ++k) v = fma(sA[k], (double)W3[k * 20 + t], v);
      v += (double)b3[t];
      v = v * ((double)g3[t] / denom) + (double)be3[t];
      v = v > 0.0 ? v : 0.0;
    }
    __syncthreads();
    if (t < 20) sB[t] = v;
    __syncthreads();

    v = 0.0;
    if (t < 15) {
#pragma unroll
      for (int k = 0; k < 20; ++k) v = fma(sB[k], (double)W4[k * 15 + t], v);
      v += (double)b4[t];
      v = v > 0.0 ? v : 0.0;
    }
    __syncthreads();
    if (t < 15) sA[t] = v;
    __syncthreads();

    if (t < 8) {
      v = 0.0;
#pragma unroll
      for (int k = 0; k < 15; ++k) v = fma(sA[k], (double)W5[k * 8 + t], v);
      v += (double)b5[t];
      double p = 1.0 / (1.0 + exp(-v));
      unsigned j = 8u * (unsigned)rb + (unsigned)t, o0, o1;
      tf2x32(0u, j, o0, o1);
      unsigned bits = o0 ^ o1;
      float u = __uint_as_float(0x3F800000u | (bits >> 9)) - 1.f;
      double thr = 1.0 - p;
      bool choice = ((double)u < thr);
      out_chosen[(size_t)rb * 8 + t] = choice ? 0.f : 1.f;
      sF[t] = choice ? thr : p;
    }
    __syncthreads();
    if (t == 0) {
      double prod = 1.0;
      for (int w2 = 0; w2 < 8; ++w2) prod *= sF[w2];
      out_logp[rb] = (float)log(prod);
    }
    __syncthreads();
  }
}

extern "C" void kernel_launch(void* const* d_in, const int* in_sizes, int n_in,
                              void* d_out, int out_size, void* d_ws, size_t ws_size,
                              hipStream_t stream) {
  const float* events = (const float*)d_in[0];
  const float* W1  = (const float*)d_in[1];
  const float* b1  = (const float*)d_in[2];
  const float* g1  = (const float*)d_in[3];
  const float* be1 = (const float*)d_in[4];
  const float* W2  = (const float*)d_in[5];
  const float* b2  = (const float*)d_in[6];
  const float* g2  = (const float*)d_in[7];
  const float* be2 = (const float*)d_in[8];
  const float* W3  = (const float*)d_in[9];
  const float* b3  = (const float*)d_in[10];
  const float* g3  = (const float*)d_in[11];
  const float* be3 = (const float*)d_in[12];
  const float* W4  = (const float*)d_in[13];
  const float* b4  = (const float*)d_in[14];
  const float* W5  = (const float*)d_in[15];
  const float* b5  = (const float*)d_in[16];

  const int B = in_sizes[0] / 32;  // 524288
  float* out = (float*)d_out;
  float* out_chosen = out;                   // (B, 8)
  float* out_logp   = out + (size_t)B * 8;   // (B,)

  const int blocks = (B + ROWS_PER_BLOCK - 1) / ROWS_PER_BLOCK;  // 1024
  hipLaunchKernelGGL(wtf_kernel, dim3(blocks), dim3(THREADS), 0, stream,
                     events, W1, b1, g1, be1, W2, b2, g2, be2,
                     W3, b3, g3, be3, W4, b4, W5, b5,
                     out_chosen, out_logp, B);
}

// Round 6
// 223.831 us; speedup vs baseline: 2.1767x; 1.0314x over previous
//
#include <hip/hip_runtime.h>
#include <math.h>

#define THREADS 256
#define TPW 4                  // 16-row tiles per wave
#define ROWS_PER_BLOCK 256     // 4 waves * TPW * 16
// bf16x3 (RTN) MFMA p-error <~2e-5 worst case; 2e-4 margin is ~10x safety.
#define P_MARGIN 2e-4f
#define FIXCAP 64

typedef float f32x4 __attribute__((ext_vector_type(4)));
typedef short short8 __attribute__((ext_vector_type(8)));
union Frag { unsigned u[4]; short8 s; };

// ---- LDS dword offsets (total pool 9812 dw = 39.2 KB -> 4 blocks/CU) ----
// Weight fragments (packed bf16 hi/lo), entry dword =
//   FB + ((kt*NT + nt)*2 + hilo)*256 + lane*4 + d, lane = kgroup*16 + (col&15)
#define FR1 0       // L1: 32x64  -> 8*256 dw
#define FR2 2048    // L2: 64x32  -> 8*256 dw
#define FR3 4096    // L3: 32x32  -> 4*256 dw
// bias/scale vectors, unpadded (overflow reads hit finite neighboring params
// which always multiply padded-ZERO weight columns -> benign)
#define VB1 5120
#define VS1 5170
#define VE1 5220
#define VB2 5270
#define VS2 5300
#define VE2 5330
#define VB3 5360
#define VS3 5380
#define VE3 5400
#define VB4 5420
#define VB5 5435
// dwords 5443..5459 = zeroed pad (covers VB5+8..15 reads)
#define ACT 5460    // per-wave act tile [feature(64)][row(16)] stride 17 = 1088 dw
#define WPOOL (ACT + 4 * 1088)  // 9812 dw
// L4/L5 fragments staged temporarily at start of ACT, then loaded to VGPRs
#define FRT4 ACT
#define FRT5 (ACT + 512)

// Exact JAX threefry2x32 (20 rounds, key schedule every 4), key = (0, 42).
__device__ __forceinline__ void tf2x32(unsigned x0, unsigned x1,
                                       unsigned &o0, unsigned &o1) {
  const unsigned k0 = 0u;
  const unsigned k1 = 42u;
  const unsigned k2 = 0x1BD11BDAu ^ k0 ^ k1;
  x0 += k0; x1 += k1;
#define TF_R(r) { x0 += x1; x1 = (x1 << (r)) | (x1 >> (32 - (r))); x1 ^= x0; }
  TF_R(13) TF_R(15) TF_R(26) TF_R(6)
  x0 += k1; x1 += k2 + 1u;
  TF_R(17) TF_R(29) TF_R(16) TF_R(24)
  x0 += k2; x1 += k0 + 2u;
  TF_R(13) TF_R(15) TF_R(26) TF_R(6)
  x0 += k0; x1 += k1 + 3u;
  TF_R(17) TF_R(29) TF_R(16) TF_R(24)
  x0 += k1; x1 += k2 + 4u;
  TF_R(13) TF_R(15) TF_R(26) TF_R(6)
  x0 += k2; x1 += k0 + 5u;
#undef TF_R
  o0 = x0; o1 = x1;
}

// bf16 round-to-nearest-even, result in top 16 bits (low 16 zero)
__device__ __forceinline__ unsigned rtnb(float v) {
  unsigned b = __float_as_uint(v);
  return (b + 0x7FFFu + ((b >> 16) & 1u)) & 0xFFFF0000u;
}

// v_cvt_pk_bf16_f32: dst = {bf16(a) low16, bf16(b) high16}, RTNE
__device__ __forceinline__ unsigned cvtpk(float a, float b) {
  unsigned r;
  asm("v_cvt_pk_bf16_f32 %0, %1, %2" : "=v"(r) : "v"(a), "v"(b));
  return r;
}

// Split 8 f32 (k-offsets 0..7) into hi/lo bf16x8 fragments (dword d = {2d,2d+1})
__device__ __forceinline__ void pack8(const float f[8], short8 &H, short8 &L) {
  Frag h, l;
#pragma unroll
  for (int d = 0; d < 4; ++d) {
    unsigned hd = cvtpk(f[2 * d], f[2 * d + 1]);
    h.u[d] = hd;
    float r0 = f[2 * d]     - __uint_as_float(hd << 16);
    float r1 = f[2 * d + 1] - __uint_as_float(hd & 0xFFFF0000u);
    l.u[d] = cvtpk(r0, r1);
  }
  H = h.s; L = l.s;
}

__device__ __forceinline__ f32x4 mfma16(short8 a, short8 b, f32x4 c) {
  return __builtin_amdgcn_mfma_f32_16x16x32_bf16(a, b, c, 0, 0, 0);
}

__device__ __forceinline__ short8 ldfrag(const float *sW, int dwoff) {
  return *reinterpret_cast<const short8 *>(sW + dwoff);
}

// Stage one weight matrix into B-fragment LDS layout (hi+lo bf16 halves).
// Zero padding comes from the pre-zeroed region (untouched slots stay 0).
template <int K, int N, int NT, int FB>
__device__ __forceinline__ void stage_layer(const float *__restrict__ W,
                                            float *sW, int t) {
  for (int i = t; i < K * N; i += THREADS) {
    int k = i / N, c = i - k * N;
    float v = W[i];
    unsigned hb = rtnb(v);
    float lov = v - __uint_as_float(hb);
    unsigned lb = rtnb(lov);
    int kt = k >> 5, gg = (k >> 3) & 3, d = (k >> 1) & 3, par = k & 1;
    int nt = c >> 4, lane = gg * 16 + (c & 15);
    int combo = kt * NT + nt;
    int dwhi = FB + (combo * 2 + 0) * 256 + lane * 4 + d;
    unsigned short *hp = reinterpret_cast<unsigned short *>(sW);
    hp[2 * dwhi + par] = (unsigned short)(hb >> 16);
    hp[2 * (dwhi + 256) + par] = (unsigned short)(lb >> 16);
  }
}

// Read A-fragment (rows=lane&15, k = kbase + (lane>>4)*8 + e) from act tile.
__device__ __forceinline__ void loadA(const float *actw, int kbase, int c,
                                      int g, short8 &H, short8 &L) {
  float f[8];
#pragma unroll
  for (int e = 0; e < 8; ++e) f[e] = actw[(kbase + g * 8 + e) * 17 + c];
  pack8(f, H, L);
}

// R5->R6: same verified MFMA math; occupancy + latency work only.
//  - LDS 47.6K -> 39.2K (L4/L5 frags to VGPRs, logits into dead act rows,
//    fp64 repair scratch aliased into act, unpadded vec params): 4 blocks/CU.
//  - grid 1024 -> 2048 blocks (TPW 8->4): halves the residency tail.
//  - X global load for tile tt+1 issued during tile tt (prefetch).
__global__ __launch_bounds__(THREADS, 2)
void wtf_kernel(const float* __restrict__ events,
                const float* __restrict__ W1, const float* __restrict__ b1,
                const float* __restrict__ g1, const float* __restrict__ be1,
                const float* __restrict__ W2, const float* __restrict__ b2,
                const float* __restrict__ g2, const float* __restrict__ be2,
                const float* __restrict__ W3, const float* __restrict__ b3,
                const float* __restrict__ g3, const float* __restrict__ be3,
                const float* __restrict__ W4, const float* __restrict__ b4,
                const float* __restrict__ W5, const float* __restrict__ b5,
                float* __restrict__ out_chosen,
                float* __restrict__ out_logp,
                int B) {
  __shared__ float sW[WPOOL];
  __shared__ unsigned s_cnt;
  __shared__ unsigned s_rows[FIXCAP];

  const int t = threadIdx.x;
  const float rden = (float)(1.0 / sqrt(1.0 + 1e-5));

  // ---- stage: zero frag+vec+L45 region, pack weights as bf16 hi/lo ----
  if (t == 0) s_cnt = 0;
  for (int i = t; i < ACT + 1024; i += THREADS) sW[i] = 0.f;
  __syncthreads();
  stage_layer<32, 50, 4, FR1>(W1, sW, t);
  stage_layer<50, 30, 2, FR2>(W2, sW, t);
  stage_layer<30, 20, 2, FR3>(W3, sW, t);
  stage_layer<20, 15, 1, FRT4>(W4, sW, t);
  stage_layer<15, 8, 1, FRT5>(W5, sW, t);
  if (t < 50)                  { sW[VB1 + t] = b1[t]; sW[VS1 + t] = g1[t] * rden; sW[VE1 + t] = be1[t]; }
  else if (t >= 64 && t < 94)  { int i = t - 64;  sW[VB2 + i] = b2[i]; sW[VS2 + i] = g2[i] * rden; sW[VE2 + i] = be2[i]; }
  else if (t >= 128 && t < 148){ int i = t - 128; sW[VB3 + i] = b3[i]; sW[VS3 + i] = g3[i] * rden; sW[VE3 + i] = be3[i]; }
  else if (t >= 192 && t < 207){ sW[VB4 + (t - 192)] = b4[t - 192]; }
  else if (t >= 224 && t < 232){ sW[VB5 + (t - 224)] = b5[t - 224]; }
  __syncthreads();

  const int w = t >> 6, lane = t & 63;
  const int c = lane & 15, g = lane >> 4;

  // L4/L5 fragments -> registers (weights shared by all waves; lane-indexed)
  const short8 bh4 = ldfrag(sW, FRT4 + lane * 4);
  const short8 bl4 = ldfrag(sW, FRT4 + 256 + lane * 4);
  const short8 bh5 = ldfrag(sW, FRT5 + lane * 4);
  const short8 bl5 = ldfrag(sW, FRT5 + 256 + lane * 4);
  __syncthreads();  // everyone's regs loaded before act region is overwritten

  float *actw = sW + ACT + w * 1088;  // [feature][row], stride 17
  float *ptw  = actw + 544;           // logits in act rows 32..63 (dead at L5)

  const int wrow0 = blockIdx.x * ROWS_PER_BLOCK + w * (TPW * 16);
  const float4 *xp = reinterpret_cast<const float4 *>(
      events + (size_t)(wrow0 + c) * 32 + g * 8);
  float4 xa = xp[0], xb = xp[1];  // tile 0; tile tt is at xp[tt*128]

#pragma unroll 1
  for (int tt = 0; tt < TPW; ++tt) {
    const int r0 = wrow0 + tt * 16;

    float xf[8] = {xa.x, xa.y, xa.z, xa.w, xb.x, xb.y, xb.z, xb.w};
    short8 Xh, Xl; pack8(xf, Xh, Xl);
    // prefetch next tile's X under this tile's compute
    const int ttn = (tt + 1 < TPW) ? tt + 1 : tt;
    xa = xp[ttn * 128]; xb = xp[ttn * 128 + 1];

    // ---- L1: (16x32)x(32x64), BN+ReLU -> act[0..63] ----
    {
      f32x4 acc[4];
#pragma unroll
      for (int nt = 0; nt < 4; ++nt) {
        float bb = sW[VB1 + nt * 16 + c];
        f32x4 ci = {bb, bb, bb, bb};
        short8 bh = ldfrag(sW, FR1 + (nt * 2 + 0) * 256 + lane * 4);
        short8 bl = ldfrag(sW, FR1 + (nt * 2 + 1) * 256 + lane * 4);
        ci = mfma16(Xl, bh, ci);
        ci = mfma16(Xh, bl, ci);
        acc[nt] = mfma16(Xh, bh, ci);
      }
#pragma unroll
      for (int nt = 0; nt < 4; ++nt) {
        float sc = sW[VS1 + nt * 16 + c], of = sW[VE1 + nt * 16 + c];
#pragma unroll
        for (int r = 0; r < 4; ++r)
          actw[(nt * 16 + c) * 17 + g * 4 + r] =
              fmaxf(fmaf(acc[nt][r], sc, of), 0.f);
      }
    }

    // ---- L2: K=64 (2 kt), N=32 (2 nt), BN+ReLU -> act[0..31] ----
    {
      f32x4 acc[2];
#pragma unroll
      for (int nt = 0; nt < 2; ++nt) {
        float bb = sW[VB2 + nt * 16 + c];
        acc[nt] = f32x4{bb, bb, bb, bb};
      }
#pragma unroll
      for (int kt = 0; kt < 2; ++kt) {
        short8 Ah, Al; loadA(actw, kt * 32, c, g, Ah, Al);
#pragma unroll
        for (int nt = 0; nt < 2; ++nt) {
          short8 bh = ldfrag(sW, FR2 + ((kt * 2 + nt) * 2 + 0) * 256 + lane * 4);
          short8 bl = ldfrag(sW, FR2 + ((kt * 2 + nt) * 2 + 1) * 256 + lane * 4);
          acc[nt] = mfma16(Al, bh, acc[nt]);
          acc[nt] = mfma16(Ah, bl, acc[nt]);
          acc[nt] = mfma16(Ah, bh, acc[nt]);
        }
      }
#pragma unroll
      for (int nt = 0; nt < 2; ++nt) {
        float sc = sW[VS2 + nt * 16 + c], of = sW[VE2 + nt * 16 + c];
#pragma unroll
        for (int r = 0; r < 4; ++r)
          actw[(nt * 16 + c) * 17 + g * 4 + r] =
              fmaxf(fmaf(acc[nt][r], sc, of), 0.f);
      }
    }

    // ---- L3: K=32, N=32, BN+ReLU -> act[0..31] ----
    {
      f32x4 acc[2];
#pragma unroll
      for (int nt = 0; nt < 2; ++nt) {
        float bb = sW[VB3 + nt * 16 + c];
        acc[nt] = f32x4{bb, bb, bb, bb};
      }
      short8 Ah, Al; loadA(actw, 0, c, g, Ah, Al);
#pragma unroll
      for (int nt = 0; nt < 2; ++nt) {
        short8 bh = ldfrag(sW, FR3 + (nt * 2 + 0) * 256 + lane * 4);
        short8 bl = ldfrag(sW, FR3 + (nt * 2 + 1) * 256 + lane * 4);
        acc[nt] = mfma16(Al, bh, acc[nt]);
        acc[nt] = mfma16(Ah, bl, acc[nt]);
        acc[nt] = mfma16(Ah, bh, acc[nt]);
      }
#pragma unroll
      for (int nt = 0; nt < 2; ++nt) {
        float sc = sW[VS3 + nt * 16 + c], of = sW[VE3 + nt * 16 + c];
#pragma unroll
        for (int r = 0; r < 4; ++r)
          actw[(nt * 16 + c) * 17 + g * 4 + r] =
              fmaxf(fmaf(acc[nt][r], sc, of), 0.f);
      }
    }

    // ---- L4: K=32, N=16, ReLU -> act[0..15]; zero act[16..31] for L5 ----
    {
      float bb = sW[VB4 + c];
      f32x4 acc = {bb, bb, bb, bb};
      short8 Ah, Al; loadA(actw, 0, c, g, Ah, Al);
      acc = mfma16(Al, bh4, acc);
      acc = mfma16(Ah, bl4, acc);
      acc = mfma16(Ah, bh4, acc);
#pragma unroll
      for (int r = 0; r < 4; ++r) {
        actw[c * 17 + g * 4 + r] = fmaxf(acc[r], 0.f);
        actw[(16 + c) * 17 + g * 4 + r] = 0.f;
      }
    }

    // ---- L5: K=32, N=16 (cols 0..7 real) -> logits to ptw ----
    {
      float bb = sW[VB5 + c];
      f32x4 acc = {bb, bb, bb, bb};
      short8 Ah, Al; loadA(actw, 0, c, g, Ah, Al);
      acc = mfma16(Al, bh5, acc);
      acc = mfma16(Ah, bl5, acc);
      acc = mfma16(Ah, bh5, acc);
      if (c < 8) {
#pragma unroll
        for (int r = 0; r < 4; ++r) ptw[(g * 4 + r) * 9 + c] = acc[r];
      }
    }

    // ---- epilogue: lane = row*4 + colpair; 2 elems/lane, all 64 useful ----
    {
      const int erow = lane >> 2, cp = lane & 3;
      const int grow = r0 + erow;
      float l0 = ptw[erow * 9 + 2 * cp];
      float l1 = ptw[erow * 9 + 2 * cp + 1];
      float p0 = 1.f / (1.f + __expf(-l0));
      float p1 = 1.f / (1.f + __expf(-l1));
      unsigned o0, o1, q0, q1;
      tf2x32(0u, 8u * (unsigned)grow + 2u * cp,      o0, o1);
      tf2x32(0u, 8u * (unsigned)grow + 2u * cp + 1u, q0, q1);
      float u0 = __uint_as_float(0x3F800000u | ((o0 ^ o1) >> 9)) - 1.f;
      float u1 = __uint_as_float(0x3F800000u | ((q0 ^ q1) >> 9)) - 1.f;
      float th0 = 1.f - p0, th1 = 1.f - p1;
      bool c0 = u0 < th0, c1 = u1 < th1;
      bool need = (fabsf(u0 - th0) < P_MARGIN) || (fabsf(u1 - th1) < P_MARGIN);
      float prod = (c0 ? th0 : p0) * (c1 ? th1 : p1);
      prod *= __shfl_xor(prod, 1);
      prod *= __shfl_xor(prod, 2);
      float2 chv = make_float2(c0 ? 0.f : 1.f, c1 ? 0.f : 1.f);
      *reinterpret_cast<float2 *>(out_chosen + (size_t)grow * 8 + 2 * cp) = chv;
      if (cp == 0) out_logp[grow] = __logf(prod);
      if (need) {
        unsigned i = atomicAdd(&s_cnt, 1u);
        if (i < FIXCAP) s_rows[i] = (unsigned)grow;
      }
    }
  }

  // ---- block-cooperative fp64 repair of flagged rows (overwrites) ----
  __syncthreads();
  unsigned cnt = s_cnt;
  if (cnt > FIXCAP) cnt = FIXCAP;
  if (cnt == 0) return;

  // scratch aliased into the (now dead) act region; ACT dword offset is even
  double *sA = reinterpret_cast<double *>(sW + ACT);
  double *sB = sA + 64;
  double *sF = sB + 64;

  const double denom = sqrt(1.0 + 1e-5);
  for (unsigned r = 0; r < cnt; ++r) {  // cnt is block-uniform
    const int rb = (int)s_rows[r];

    if (t < 32) sA[t] = (double)events[(size_t)rb * 32 + t];
    __syncthreads();

    double v = 0.0;
    if (t < 50) {
#pragma unroll
      for (int k = 0; k < 32; ++k) v = fma(sA[k], (double)W1[k * 50 + t], v);
      v += (double)b1[t];
      v = v * ((double)g1[t] / denom) + (double)be1[t];
      v = v > 0.0 ? v : 0.0;
    }
    __syncthreads();
    if (t < 50) sB[t] = v;
    __syncthreads();

    v = 0.0;
    if (t < 30) {
#pragma unroll
      for (int k = 0; k < 50; ++k) v = fma(sB[k], (double)W2[k * 30 + t], v);
      v += (double)b2[t];
      v = v * ((double)g2[t] / denom) + (double)be2[t];
      v = v > 0.0 ? v : 0.0;
    }
    __syncthreads();
    if (t < 30) sA[t] = v;
    __syncthreads();

    v = 0.0;
    if (t < 20) {
#pragma unroll
      for (int k = 0; k < 30; ++k) v = fma(sA[k], (double)W3[k * 20 + t], v);
      v += (double)b3[t];
      v = v * ((double)g3[t] / denom) + (double)be3[t];
      v = v > 0.0 ? v : 0.0;
    }
    __syncthreads();
    if (t < 20) sB[t] = v;
    __syncthreads();

    v = 0.0;
    if (t < 15) {
#pragma unroll
      for (int k = 0; k < 20; ++k) v = fma(sB[k], (double)W4[k * 15 + t], v);
      v += (double)b4[t];
      v = v > 0.0 ? v : 0.0;
    }
    __syncthreads();
    if (t < 15) sA[t] = v;
    __syncthreads();

    if (t < 8) {
      v = 0.0;
#pragma unroll
      for (int k = 0; k < 15; ++k) v = fma(sA[k], (double)W5[k * 8 + t], v);
      v += (double)b5[t];
      double p = 1.0 / (1.0 + exp(-v));
      unsigned j = 8u * (unsigned)rb + (unsigned)t, o0, o1;
      tf2x32(0u, j, o0, o1);
      unsigned bits = o0 ^ o1;
      float u = __uint_as_float(0x3F800000u | (bits >> 9)) - 1.f;
      double thr = 1.0 - p;
      bool choice = ((double)u < thr);
      out_chosen[(size_t)rb * 8 + t] = choice ? 0.f : 1.f;
      sF[t] = choice ? thr : p;
    }
    __syncthreads();
    if (t == 0) {
      double prod = 1.0;
      for (int w2 = 0; w2 < 8; ++w2) prod *= sF[w2];
      out_logp[rb] = (float)log(prod);
    }
    __syncthreads();
  }
}

extern "C" void kernel_launch(void* const* d_in, const int* in_sizes, int n_in,
                              void* d_out, int out_size, void* d_ws, size_t ws_size,
                              hipStream_t stream) {
  const float* events = (const float*)d_in[0];
  const float* W1  = (const float*)d_in[1];
  const float* b1  = (const float*)d_in[2];
  const float* g1  = (const float*)d_in[3];
  const float* be1 = (const float*)d_in[4];
  const float* W2  = (const float*)d_in[5];
  const float* b2  = (const float*)d_in[6];
  const float* g2  = (const float*)d_in[7];
  const float* be2 = (const float*)d_in[8];
  const float* W3  = (const float*)d_in[9];
  const float* b3  = (const float*)d_in[10];
  const float* g3  = (const float*)d_in[11];
  const float* be3 = (const float*)d_in[12];
  const float* W4  = (const float*)d_in[13];
  const float* b4  = (const float*)d_in[14];
  const float* W5  = (const float*)d_in[15];
  const float* b5  = (const float*)d_in[16];

  const int B = in_sizes[0] / 32;  // 524288
  float* out = (float*)d_out;
  float* out_chosen = out;                   // (B, 8)
  float* out_logp   = out + (size_t)B * 8;   // (B,)

  const int blocks = (B + ROWS_PER_BLOCK - 1) / ROWS_PER_BLOCK;  // 2048
  hipLaunchKernelGGL(wtf_kernel, dim3(blocks), dim3(THREADS), 0, stream,
                     events, W1, b1, g1, be1, W2, b2, g2, be2,
                     W3, b3, g3, be3, W4, b4, W5, b5,
                     out_chosen, out_logp, B);
}

// Round 7
// 222.901 us; speedup vs baseline: 2.1858x; 1.0042x over previous
//
#include <hip/hip_runtime.h>
#include <math.h>

#define THREADS 256
#define TPW 4                  // 16-row tiles per wave
#define ROWS_PER_BLOCK 256     // 4 waves * TPW * 16
// bf16x3 (RTN) MFMA p-error <~2e-5 worst case; 2e-4 margin is ~10x safety.
#define P_MARGIN 2e-4f
#define FIXCAP 64

typedef float f32x4 __attribute__((ext_vector_type(4)));
typedef short short8 __attribute__((ext_vector_type(8)));
union Frag { unsigned u[4]; short8 s; };

// ---- LDS dword offsets ----
// Weight A-fragments (W^T, bf16 hi/lo), entry dword =
//   FB + (combo*2 + hilo)*256 + lane*4 + d,  combo = kt*NT + tile
// Inner layers' out-features are PERMUTED into tiles so that the D result of
// layer L is, lane-locally, the B-fragment of layer L+1:
//   tile t, row r  <->  feature (r>>2)*8 + (r&3) + t*4   (within a 32-feat pg)
#define FR1 0       // L1: K=32,N=64p:  4 tiles -> 2048 dw
#define FR2 2048    // L2: K=64p,N=32p: 2kt*2t  -> 2048 dw
#define FR3 4096    // L3: K=32p,N=32p: 2 tiles -> 1024 dw
#define FR4 5120    // L4: K=32p,N=32p: 2 tiles -> 1024 dw
#define FR5 6144    // L5: K=32p,N=16p: 1 tile  -> 512 dw (identity col map)
#define VB1 6656
#define VS1 6708
#define VE1 6760
#define VB2 6812
#define VS2 6844
#define VE2 6876
#define VB3 6908
#define VS3 6928
#define VE3 6948
#define VB4 6968
#define VB5 6984
#define PZ  6992    // 32 dw zero pad (absorbs padded-feature param reads)
#define WPOOL 7024  // 28096 B

// Exact JAX threefry2x32 (20 rounds, key schedule every 4), key = (0, 42).
__device__ __forceinline__ void tf2x32(unsigned x0, unsigned x1,
                                       unsigned &o0, unsigned &o1) {
  const unsigned k0 = 0u;
  const unsigned k1 = 42u;
  const unsigned k2 = 0x1BD11BDAu ^ k0 ^ k1;
  x0 += k0; x1 += k1;
#define TF_R(r) { x0 += x1; x1 = (x1 << (r)) | (x1 >> (32 - (r))); x1 ^= x0; }
  TF_R(13) TF_R(15) TF_R(26) TF_R(6)
  x0 += k1; x1 += k2 + 1u;
  TF_R(17) TF_R(29) TF_R(16) TF_R(24)
  x0 += k2; x1 += k0 + 2u;
  TF_R(13) TF_R(15) TF_R(26) TF_R(6)
  x0 += k0; x1 += k1 + 3u;
  TF_R(17) TF_R(29) TF_R(16) TF_R(24)
  x0 += k1; x1 += k2 + 4u;
  TF_R(13) TF_R(15) TF_R(26) TF_R(6)
  x0 += k2; x1 += k0 + 5u;
#undef TF_R
  o0 = x0; o1 = x1;
}

// bf16 round-to-nearest-even, result in top 16 bits (low 16 zero)
__device__ __forceinline__ unsigned rtnb(float v) {
  unsigned b = __float_as_uint(v);
  return (b + 0x7FFFu + ((b >> 16) & 1u)) & 0xFFFF0000u;
}

// v_cvt_pk_bf16_f32: dst = {bf16(a) low16, bf16(b) high16}, RTNE
__device__ __forceinline__ unsigned cvtpk(float a, float b) {
  unsigned r;
  asm("v_cvt_pk_bf16_f32 %0, %1, %2" : "=v"(r) : "v"(a), "v"(b));
  return r;
}

// Split 8 f32 (k-offsets 0..7) into hi/lo bf16x8 fragments (dword d={2d,2d+1})
__device__ __forceinline__ void pack8(const float f[8], short8 &H, short8 &L) {
  Frag h, l;
#pragma unroll
  for (int d = 0; d < 4; ++d) {
    unsigned hd = cvtpk(f[2 * d], f[2 * d + 1]);
    h.u[d] = hd;
    float r0 = f[2 * d]     - __uint_as_float(hd << 16);
    float r1 = f[2 * d + 1] - __uint_as_float(hd & 0xFFFF0000u);
    l.u[d] = cvtpk(r0, r1);
  }
  H = h.s; L = l.s;
}

__device__ __forceinline__ f32x4 mfma16(short8 a, short8 b, f32x4 c) {
  return __builtin_amdgcn_mfma_f32_16x16x32_bf16(a, b, c, 0, 0, 0);
}

__device__ __forceinline__ short8 ldfrag(const float *sW, int dwoff) {
  return *reinterpret_cast<const short8 *>(sW + dwoff);
}
__device__ __forceinline__ f32x4 ldv4(const float *sW, int dwoff) {
  return *reinterpret_cast<const f32x4 *>(sW + dwoff);
}

// Stage W as A-fragments of W^T (lane l: A[row=l&15][k=(l>>4)*8+e]).
// PERM: inner layers map out-feature n -> (tile, row) s.t. D regs chain
// lane-locally into the next layer's B-frag. Unstaged slots stay zero.
template <int K, int N, int NT, int FB, bool PERM>
__device__ __forceinline__ void stageA(const float *__restrict__ W,
                                       float *sW, int t) {
  for (int i = t; i < K * N; i += THREADS) {
    int k = i / N, n = i - k * N;
    float v = W[i];
    unsigned hb = rtnb(v);
    unsigned lb = rtnb(v - __uint_as_float(hb));
    int kt = k >> 5, g = (k >> 3) & 3, e = k & 7, d = e >> 1, par = e & 1;
    int tile, r;
    if (PERM) {
      int pg = n >> 5, m = n & 31, tt = (m >> 2) & 1;
      r = ((m >> 3) << 2) | (m & 3);
      tile = pg * 2 + tt;
    } else {
      tile = n >> 4; r = n & 15;
    }
    int lane = g * 16 + r;
    int dwhi = FB + (kt * NT + tile) * 512 + lane * 4 + d;
    unsigned short *hp = reinterpret_cast<unsigned short *>(sW);
    hp[2 * dwhi + par] = (unsigned short)(hb >> 16);
    hp[2 * (dwhi + 256) + par] = (unsigned short)(lb >> 16);
  }
}

// BN+ReLU two acc tiles (t0,t1 of one 32-feature pg) and pack to B-frag.
__device__ __forceinline__ void bnpack(f32x4 a0, f32x4 a1, const float *sW,
                                       int vs, int ve, int g,
                                       short8 &H, short8 &L) {
  f32x4 sc0 = ldv4(sW, vs + g * 8),     of0 = ldv4(sW, ve + g * 8);
  f32x4 sc1 = ldv4(sW, vs + g * 8 + 4), of1 = ldv4(sW, ve + g * 8 + 4);
  float f[8];
#pragma unroll
  for (int q = 0; q < 4; ++q) {
    f[q]     = fmaxf(fmaf(a0[q], sc0[q], of0[q]), 0.f);
    f[4 + q] = fmaxf(fmaf(a1[q], sc1[q], of1[q]), 0.f);
  }
  pack8(f, H, L);
}

// R6->R7: swapped-operand MFMA chain (D = W^T x act^T, batch stays in cols).
// Column-permuted weight staging makes every layer->layer handoff LANE-LOCAL:
// no activation LDS tile, no scalar act reads, no bank conflicts.
__global__ __launch_bounds__(THREADS, 2)
void wtf_kernel(const float* __restrict__ events,
                const float* __restrict__ W1, const float* __restrict__ b1,
                const float* __restrict__ g1, const float* __restrict__ be1,
                const float* __restrict__ W2, const float* __restrict__ b2,
                const float* __restrict__ g2, const float* __restrict__ be2,
                const float* __restrict__ W3, const float* __restrict__ b3,
                const float* __restrict__ g3, const float* __restrict__ be3,
                const float* __restrict__ W4, const float* __restrict__ b4,
                const float* __restrict__ W5, const float* __restrict__ b5,
                float* __restrict__ out_chosen,
                float* __restrict__ out_logp,
                int B) {
  __shared__ float sW[WPOOL];
  __shared__ unsigned s_cnt;
  __shared__ unsigned s_rows[FIXCAP];
  __shared__ double sA[64];
  __shared__ double sB[64];
  __shared__ double sF[8];

  const int t = threadIdx.x;
  const float rden = (float)(1.0 / sqrt(1.0 + 1e-5));

  if (t == 0) s_cnt = 0;
  for (int i = t; i < WPOOL; i += THREADS) sW[i] = 0.f;
  __syncthreads();
  stageA<32, 50, 4, FR1, true>(W1, sW, t);
  stageA<50, 30, 2, FR2, true>(W2, sW, t);
  stageA<30, 20, 2, FR3, true>(W3, sW, t);
  stageA<20, 15, 2, FR4, true>(W4, sW, t);
  stageA<15,  8, 1, FR5, false>(W5, sW, t);
  if (t < 50)                  { sW[VB1 + t] = b1[t]; sW[VS1 + t] = g1[t] * rden; sW[VE1 + t] = be1[t]; }
  else if (t >= 64 && t < 94)  { int i = t - 64;  sW[VB2 + i] = b2[i]; sW[VS2 + i] = g2[i] * rden; sW[VE2 + i] = be2[i]; }
  else if (t >= 128 && t < 148){ int i = t - 128; sW[VB3 + i] = b3[i]; sW[VS3 + i] = g3[i] * rden; sW[VE3 + i] = be3[i]; }
  else if (t >= 192 && t < 207){ sW[VB4 + (t - 192)] = b4[t - 192]; }
  else if (t >= 224 && t < 232){ sW[VB5 + (t - 224)] = b5[t - 224]; }
  __syncthreads();

  const int w = t >> 6, lane = t & 63;
  const int c = lane & 15, g = lane >> 4;
  const int labase = lane * 4;

  const int wrow0 = blockIdx.x * ROWS_PER_BLOCK + w * (TPW * 16);
  const float4 *xp = reinterpret_cast<const float4 *>(
      events + (size_t)(wrow0 + c) * 32 + g * 8);
  float4 xa = xp[0], xb = xp[1];  // tile tt lives at xp[tt*128]

#pragma unroll 1
  for (int tt = 0; tt < TPW; ++tt) {
    const int r0 = wrow0 + tt * 16;
    const int row = r0 + c;

    // ---- X B-frag straight from global: col=batch row0+c, k=g*8+e ----
    float xf[8] = {xa.x, xa.y, xa.z, xa.w, xb.x, xb.y, xb.z, xb.w};
    short8 Xh, Xl; pack8(xf, Xh, Xl);
    const int ttn = (tt + 1 < TPW) ? tt + 1 : tt;
    xa = xp[ttn * 128]; xb = xp[ttn * 128 + 1];

    // ---- L1: 4 permuted out-tiles (feats pg*32 + g*8 + t*4 + q) ----
    f32x4 a1[4];
#pragma unroll
    for (int ti = 0; ti < 4; ++ti) {
      f32x4 acc = ldv4(sW, VB1 + (ti >> 1) * 32 + g * 8 + (ti & 1) * 4);
      short8 wh = ldfrag(sW, FR1 + ti * 512 + labase);
      short8 wl = ldfrag(sW, FR1 + ti * 512 + 256 + labase);
      acc = mfma16(wh, Xl, acc);
      acc = mfma16(wl, Xh, acc);
      a1[ti] = mfma16(wh, Xh, acc);
    }

    // ---- L1 -> L2 B-frags (lane-local!), K=64 = 2 kt ----
    short8 B2h[2], B2l[2];
    bnpack(a1[0], a1[1], sW, VS1,      VE1,      g, B2h[0], B2l[0]);
    bnpack(a1[2], a1[3], sW, VS1 + 32, VE1 + 32, g, B2h[1], B2l[1]);

    // ---- L2: 2 out-tiles x 2 kt ----
    f32x4 a2[2];
#pragma unroll
    for (int ti = 0; ti < 2; ++ti) {
      f32x4 acc = ldv4(sW, VB2 + g * 8 + ti * 4);
#pragma unroll
      for (int kt = 0; kt < 2; ++kt) {
        short8 wh = ldfrag(sW, FR2 + (kt * 2 + ti) * 512 + labase);
        short8 wl = ldfrag(sW, FR2 + (kt * 2 + ti) * 512 + 256 + labase);
        acc = mfma16(wh, B2l[kt], acc);
        acc = mfma16(wl, B2h[kt], acc);
        acc = mfma16(wh, B2h[kt], acc);
      }
      a2[ti] = acc;
    }

    // ---- L2 -> L3 ----
    short8 B3h, B3l;
    bnpack(a2[0], a2[1], sW, VS2, VE2, g, B3h, B3l);

    // ---- L3: 2 out-tiles ----
    f32x4 a3[2];
#pragma unroll
    for (int ti = 0; ti < 2; ++ti) {
      f32x4 acc = ldv4(sW, VB3 + g * 8 + ti * 4);
      short8 wh = ldfrag(sW, FR3 + ti * 512 + labase);
      short8 wl = ldfrag(sW, FR3 + ti * 512 + 256 + labase);
      acc = mfma16(wh, B3l, acc);
      acc = mfma16(wl, B3h, acc);
      a3[ti] = mfma16(wh, B3h, acc);
    }

    // ---- L3 -> L4 ----
    short8 B4h, B4l;
    bnpack(a3[0], a3[1], sW, VS3, VE3, g, B4h, B4l);

    // ---- L4: 2 out-tiles (15 real feats spread over 32 slots), ReLU ----
    f32x4 a4[2];
#pragma unroll
    for (int ti = 0; ti < 2; ++ti) {
      f32x4 acc = ldv4(sW, VB4 + g * 8 + ti * 4);
      short8 wh = ldfrag(sW, FR4 + ti * 512 + labase);
      short8 wl = ldfrag(sW, FR4 + ti * 512 + 256 + labase);
      acc = mfma16(wh, B4l, acc);
      acc = mfma16(wl, B4h, acc);
      a4[ti] = mfma16(wh, B4h, acc);
    }

    // ---- L4 -> L5 (ReLU only, no BN) ----
    short8 B5h, B5l;
    {
      float f[8];
#pragma unroll
      for (int q = 0; q < 4; ++q) {
        f[q]     = fmaxf(a4[0][q], 0.f);
        f[4 + q] = fmaxf(a4[1][q], 0.f);
      }
      pack8(f, B5h, B5l);
    }

    // ---- L5: identity col map -> lane holds logits g*4+q (g<2 real) ----
    f32x4 a5;
    {
      f32x4 acc = ldv4(sW, VB5 + g * 4);
      short8 wh = ldfrag(sW, FR5 + labase);
      short8 wl = ldfrag(sW, FR5 + 256 + labase);
      acc = mfma16(wh, B5l, acc);
      acc = mfma16(wl, B5h, acc);
      a5 = mfma16(wh, B5h, acc);
    }

    // ---- epilogue: redistribute 8 logits/row to 2/lane, all 64 busy ----
    {
      float s2v = __shfl_xor(a5[2], 32);
      float s3v = __shfl_xor(a5[3], 32);
      float l0 = (g < 2) ? a5[0] : s2v;
      float l1 = (g < 2) ? a5[1] : s3v;
      const int base = ((g & 1) << 2) | ((g >> 1) << 1);  // 0,4,2,6
      float p0 = 1.f / (1.f + __expf(-l0));
      float p1 = 1.f / (1.f + __expf(-l1));
      unsigned o0, o1, q0, q1;
      tf2x32(0u, 8u * (unsigned)row + (unsigned)base,      o0, o1);
      tf2x32(0u, 8u * (unsigned)row + (unsigned)base + 1u, q0, q1);
      float u0 = __uint_as_float(0x3F800000u | ((o0 ^ o1) >> 9)) - 1.f;
      float u1 = __uint_as_float(0x3F800000u | ((q0 ^ q1) >> 9)) - 1.f;
      float th0 = 1.f - p0, th1 = 1.f - p1;
      bool c0 = u0 < th0, c1 = u1 < th1;
      bool need = (fabsf(u0 - th0) < P_MARGIN) || (fabsf(u1 - th1) < P_MARGIN);
      float prod = (c0 ? th0 : p0) * (c1 ? th1 : p1);
      prod *= __shfl_xor(prod, 16);
      prod *= __shfl_xor(prod, 32);
      float2 chv = make_float2(c0 ? 0.f : 1.f, c1 ? 0.f : 1.f);
      *reinterpret_cast<float2 *>(out_chosen + (size_t)row * 8 + base) = chv;
      if (g == 0) out_logp[row] = __logf(prod);
      if (need) {  // dup rows possible (4 lanes/row) -> repair is idempotent
        unsigned i = atomicAdd(&s_cnt, 1u);
        if (i < FIXCAP) s_rows[i] = (unsigned)row;
      }
    }
  }

  // ---- block-cooperative fp64 repair of flagged rows (overwrites) ----
  __syncthreads();
  unsigned cnt = s_cnt;
  if (cnt > FIXCAP) cnt = FIXCAP;
  if (cnt == 0) return;

  const double denom = sqrt(1.0 + 1e-5);
  for (unsigned r = 0; r < cnt; ++r) {  // cnt is block-uniform
    const int rb = (int)s_rows[r];

    if (t < 32) sA[t] = (double)events[(size_t)rb * 32 + t];
    __syncthreads();

    double v = 0.0;
    if (t < 50) {
#pragma unroll
      for (int k = 0; k < 32; ++k) v = fma(sA[k], (double)W1[k * 50 + t], v);
      v += (double)b1[t];
      v = v * ((double)g1[t] / denom) + (double)be1[t];
      v = v > 0.0 ? v : 0.0;
    }
    __syncthreads();
    if (t < 50) sB[t] = v;
    __syncthreads();

    v = 0.0;
    if (t < 30) {
#pragma unroll
      for (int k = 0; k < 50; ++k) v = fma(sB[k], (double)W2[k * 30 + t], v);
      v += (double)b2[t];
      v = v * ((double)g2[t] / denom) + (double)be2[t];
      v = v > 0.0 ? v : 0.0;
    }
    __syncthreads();
    if (t < 30) sA[t] = v;
    __syncthreads();

    v = 0.0;
    if (t < 20) {
#pragma unroll
      for (int k = 0; k < 30; ++k) v = fma(sA[k], (double)W3[k * 20 + t], v);
      v += (double)b3[t];
      v = v * ((double)g3[t] / denom) + (double)be3[t];
      v = v > 0.0 ? v : 0.0;
    }
    __syncthreads();
    if (t < 20) sB[t] = v;
    __syncthreads();

    v = 0.0;
    if (t < 15) {
#pragma unroll
      for (int k = 0; k < 20; ++k) v = fma(sB[k], (double)W4[k * 15 + t], v);
      v += (double)b4[t];
      v = v > 0.0 ? v : 0.0;
    }
    __syncthreads();
    if (t < 15) sA[t] = v;
    __syncthreads();

    if (t < 8) {
      v = 0.0;
#pragma unroll
      for (int k = 0; k < 15; ++k) v = fma(sA[k], (double)W5[k * 8 + t], v);
      v += (double)b5[t];
      double p = 1.0 / (1.0 + exp(-v));
      unsigned j = 8u * (unsigned)rb + (unsigned)t, o0, o1;
      tf2x32(0u, j, o0, o1);
      unsigned bits = o0 ^ o1;
      float u = __uint_as_float(0x3F800000u | (bits >> 9)) - 1.f;
      double thr = 1.0 - p;
      bool choice = ((double)u < thr);
      out_chosen[(size_t)rb * 8 + t] = choice ? 0.f : 1.f;
      sF[t] = choice ? thr : p;
    }
    __syncthreads();
    if (t == 0) {
      double prod = 1.0;
      for (int w2 = 0; w2 < 8; ++w2) prod *= sF[w2];
      out_logp[rb] = (float)log(prod);
    }
    __syncthreads();
  }
}

extern "C" void kernel_launch(void* const* d_in, const int* in_sizes, int n_in,
                              void* d_out, int out_size, void* d_ws, size_t ws_size,
                              hipStream_t stream) {
  const float* events = (const float*)d_in[0];
  const float* W1  = (const float*)d_in[1];
  const float* b1  = (const float*)d_in[2];
  const float* g1  = (const float*)d_in[3];
  const float* be1 = (const float*)d_in[4];
  const float* W2  = (const float*)d_in[5];
  const float* b2  = (const float*)d_in[6];
  const float* g2  = (const float*)d_in[7];
  const float* be2 = (const float*)d_in[8];
  const float* W3  = (const float*)d_in[9];
  const float* b3  = (const float*)d_in[10];
  const float* g3  = (const float*)d_in[11];
  const float* be3 = (const float*)d_in[12];
  const float* W4  = (const float*)d_in[13];
  const float* b4  = (const float*)d_in[14];
  const float* W5  = (const float*)d_in[15];
  const float* b5  = (const float*)d_in[16];

  const int B = in_sizes[0] / 32;  // 524288
  float* out = (float*)d_out;
  float* out_chosen = out;                   // (B, 8)
  float* out_logp   = out + (size_t)B * 8;   // (B,)

  const int blocks = (B + ROWS_PER_BLOCK - 1) / ROWS_PER_BLOCK;  // 2048
  hipLaunchKernelGGL(wtf_kernel, dim3(blocks), dim3(THREADS), 0, stream,
                     events, W1, b1, g1, be1, W2, b2, g2, be2,
                     W3, b3, g3, be3, W4, b4, W5, b5,
                     out_chosen, out_logp, B);
}